// Round 1
// baseline (280.952 us; speedup 1.0000x reference)
//
#include <hip/hip_runtime.h>

// Problem constants (from reference setup_inputs)
constexpr int B = 16;
constexpr int D = 256;
constexpr int K = 18;
constexpr int SZ = 128;
constexpr int S = SZ * SZ;      // 16384 positions per plane
constexpr int N = S / 2;        // 8192 sampled positions

// ---------------------------------------------------------------------------
// Phase 2: per sampled position, argmin over K prototypes of squared distance.
// d2 = p2[k] - 2*cross[k] (+ f2, constant over k -> dropped).
// fp64 accumulation so near-ties resolve identically to a high-precision ref.
// Writes winning k (int8) into table[b*S + pos]; table pre-set to -1.
// ---------------------------------------------------------------------------
__global__ __launch_bounds__(256) void argmin_kernel(
    const float* __restrict__ assp,
    const float* __restrict__ proto,
    const int* __restrict__ idx,
    signed char* __restrict__ table) {
  __shared__ double spd[K * D];   // 36 KiB: prototypes as fp64
  __shared__ double sp2[K];       // ||p_k||^2

  // b = blockIdx % 16 => all 32 blocks of a batch land on the same XCD
  // (round-robin dispatch: xcd = blockIdx % 8), maximizing L2 plane reuse.
  const int b  = blockIdx.x & 15;
  const int nb = blockIdx.x >> 4;   // 0..31

  const float* pb = proto + (size_t)b * K * D;
  for (int i = threadIdx.x; i < K * D; i += 256)
    spd[i] = (double)pb[i];
  __syncthreads();

  if (threadIdx.x < K) {
    double s = 0.0;
    const double* row = &spd[threadIdx.x * D];
    for (int d = 0; d < D; ++d) s += row[d] * row[d];
    sp2[threadIdx.x] = s;
  }
  __syncthreads();

  const int n   = nb * 256 + threadIdx.x;   // 0..8191
  const int pos = idx[n];                   // 0..16383 (x*128+y == flat idx)
  const float* fb = assp + (size_t)b * D * S + pos;

  double acc[K];
#pragma unroll
  for (int k = 0; k < K; ++k) acc[k] = 0.0;

#pragma unroll 4
  for (int d = 0; d < D; ++d) {
    const double fv = (double)fb[(size_t)d * S];
#pragma unroll
    for (int k = 0; k < K; ++k) acc[k] += fv * spd[k * D + d];
  }

  double best = 1e300;
  int bi = 0;
#pragma unroll
  for (int k = 0; k < K; ++k) {
    const double d2 = sp2[k] - 2.0 * acc[k];
    if (d2 < best) { best = d2; bi = k; }   // strict '<' => first-min, matches argmin
  }
  table[(size_t)b * S + pos] = (signed char)bi;
}

// ---------------------------------------------------------------------------
// Phase 3: one block per (b,d) plane. out = in, except table[pos]>=0 =>
// out = proto[b][k][d]. Fully coalesced float4 read/modify/write.
// ---------------------------------------------------------------------------
__global__ __launch_bounds__(256) void scatter_kernel(
    const float* __restrict__ assp,
    const float* __restrict__ proto,
    const signed char* __restrict__ table,
    float* __restrict__ out) {
  const int bd = blockIdx.x;      // 0..B*D-1
  const int b  = bd >> 8;         // /D
  const int d  = bd & 255;        // %D

  __shared__ float sp[K];
  if (threadIdx.x < K)
    sp[threadIdx.x] = proto[((size_t)b * K + threadIdx.x) * D + d];
  __syncthreads();

  const signed char* tb = table + (size_t)b * S;
  const float4* in4 = (const float4*)(assp + (size_t)bd * S);
  float4* out4 = (float4*)(out + (size_t)bd * S);

#pragma unroll
  for (int it = 0; it < S / 4 / 256; ++it) {   // 16 iterations
    const int i = it * 256 + threadIdx.x;      // float4 index within plane
    char4 t;
    *(int*)&t = ((const int*)tb)[i];
    float4 v = in4[i];
    if (t.x >= 0) v.x = sp[(int)t.x];
    if (t.y >= 0) v.y = sp[(int)t.y];
    if (t.z >= 0) v.z = sp[(int)t.z];
    if (t.w >= 0) v.w = sp[(int)t.w];
    out4[i] = v;
  }
}

extern "C" void kernel_launch(void* const* d_in, const int* in_sizes, int n_in,
                              void* d_out, int out_size, void* d_ws, size_t ws_size,
                              hipStream_t stream) {
  const float* assp  = (const float*)d_in[0];
  const float* proto = (const float*)d_in[1];
  const int*   idx   = (const int*)d_in[2];
  float* out = (float*)d_out;
  signed char* table = (signed char*)d_ws;   // B*S = 256 KiB

  // table := -1 everywhere (0xFF == (int8)-1)
  hipMemsetAsync(table, 0xFF, (size_t)B * S, stream);

  argmin_kernel<<<B * N / 256, 256, 0, stream>>>(assp, proto, idx, table);
  scatter_kernel<<<B * D, 256, 0, stream>>>(assp, proto, table, out);
}